// Round 3
// baseline (68.157 us; speedup 1.0000x reference)
//
#include <hip/hip_runtime.h>

// ConditionalSplineSQ2D: B=32, M=16, K=32, Kc=31, 136 triu pairs of 16.
// Outputs concatenated: poly [32,16,2,31,4] = 126976 floats, then
// Z [32,16,31,31] = 492032 floats.

#define BM_TOTAL 512   // B*M
#define KC 31
#define NPAIR 136
#define POLY_ITEMS 31744   // BM_TOTAL * 2 * KC  (one float4 each)
#define POLY_FLOATS 126976 // POLY_ITEMS * 4
#define Z_STRIDE 961       // KC*KC

__global__ __launch_bounds__(256) void spline_sq2d_kernel(
    const float* __restrict__ params,   // [512, 2, 32, 2]
    const float* __restrict__ knots,    // [32, 2]
    const float* __restrict__ coeffs,   // [31, 31, 136]
    float* __restrict__ out)            // [126976 + 492032]
{
    const int tid = threadIdx.x;
    const int blk = blockIdx.x;

    // ------------------------------------------------------------------
    // Fused side-task: poly output. First 124 blocks, 1 float4 per thread.
    // gid = (bm*2+dim)*31 + k ; matches flat float4 index of [512,2,31,4].
    // ------------------------------------------------------------------
    if (blk < (POLY_ITEMS / 256)) {
        const int gid = blk * 256 + tid;          // 0..31743
        const int k   = gid % KC;
        const int rem = gid / KC;                 // bm*2 + dim
        const int dim = rem & 1;
        const float* p = params + (rem * 32 + k) * 2;   // 8B aligned
        const float2 v0 = *(const float2*)(p);
        const float2 v1 = *(const float2*)(p + 2);
        const float y0 = v0.x, d0 = v0.y, y1 = v1.x, d1 = v1.y;
        const float h  = knots[(k + 1) * 2 + dim] - knots[k * 2 + dim];
        // Exact reference associativity: 3*(y1-y0)/(h*h) - (2*d0+d1)/h, etc.
        const float c2 = 3.0f * (y1 - y0) / (h * h) - (2.0f * d0 + d1) / h;
        const float c3 = 2.0f * (y0 - y1) / (h * h * h) + (d0 + d1) / (h * h);
        float4 o; o.x = y0; o.y = d0; o.z = c2; o.w = c3;
        ((float4*)out)[gid] = o;
    }

    // ------------------------------------------------------------------
    // Z part: one block per (i,j). coeffs[i][j][:] staged once in LDS.
    // ------------------------------------------------------------------
    __shared__ float cf[NPAIR];
    if (tid < NPAIR) cf[tid] = coeffs[blk * NPAIR + tid];
    __syncthreads();

    const int i = blk / KC;
    const int j = blk % KC;

    // h values are uniform across the block (scalar-broadcast loads).
    const float hx = knots[(i + 1) * 2 + 0] - knots[i * 2 + 0];
    const float hy = knots[(j + 1) * 2 + 1] - knots[j * 2 + 1];
    const float ihx = 1.0f / hx, ihx2 = ihx * ihx, ihx3 = ihx2 * ihx;
    const float ihy = 1.0f / hy, ihy2 = ihy * ihy, ihy3 = ihy2 * ihy;

    float* __restrict__ zout = out + POLY_FLOATS;

    for (int bm = tid; bm < BM_TOTAL; bm += 256) {
        // x-dim Hermite coeffs at interval i
        const float* px = params + (bm * 64 + i) * 2;         // dim 0
        const float2 a0 = *(const float2*)px;
        const float2 a1 = *(const float2*)(px + 2);
        // y-dim Hermite coeffs at interval j
        const float* py = params + (bm * 64 + 32 + j) * 2;    // dim 1
        const float2 b0 = *(const float2*)py;
        const float2 b1 = *(const float2*)(py + 2);

        float cx[4], cy[4];
        cx[0] = a0.x;
        cx[1] = a0.y;
        cx[2] = 3.0f * (a1.x - a0.x) * ihx2 - (2.0f * a0.y + a1.y) * ihx;
        cx[3] = 2.0f * (a0.x - a1.x) * ihx3 + (a0.y + a1.y) * ihx2;
        cy[0] = b0.x;
        cy[1] = b0.y;
        cy[2] = 3.0f * (b1.x - b0.x) * ihy2 - (2.0f * b0.y + b1.y) * ihy;
        cy[3] = 2.0f * (b0.x - b1.x) * ihy3 + (b0.y + b1.y) * ihy2;

        // G16[4a + c] = cx[a] * cy[c]
        float g[16];
        #pragma unroll
        for (int a = 0; a < 4; ++a)
            #pragma unroll
            for (int c = 0; c < 4; ++c)
                g[a * 4 + c] = cx[a] * cy[c];

        // triu(16) pair sum, row-major order (u, v>=u) — matches np.triu_indices.
        float sum = 0.0f;
        int p = 0;
        #pragma unroll
        for (int u = 0; u < 16; ++u) {
            const float gu = g[u];
            #pragma unroll
            for (int v = u; v < 16; ++v) {
                sum = fmaf(gu * g[v], cf[p], sum);
                ++p;
            }
        }

        zout[bm * Z_STRIDE + blk] = sum;
    }
}

extern "C" void kernel_launch(void* const* d_in, const int* in_sizes, int n_in,
                              void* d_out, int out_size, void* d_ws, size_t ws_size,
                              hipStream_t stream) {
    const float* params = (const float*)d_in[0];
    const float* knots  = (const float*)d_in[1];
    const float* coeffs = (const float*)d_in[2];
    float* out = (float*)d_out;
    (void)in_sizes; (void)n_in; (void)out_size; (void)d_ws; (void)ws_size;

    spline_sq2d_kernel<<<KC * KC, 256, 0, stream>>>(params, knots, coeffs, out);
}